// Round 1
// baseline (1026.248 us; speedup 1.0000x reference)
//
#include <hip/hip_runtime.h>
#include <hip/hip_bf16.h>

typedef float f32x4 __attribute__((ext_vector_type(4)));
typedef short bf16x8 __attribute__((ext_vector_type(8)));

#define NB 4
#define NC 64
#define NH 128
#define NW 128
#define NN 4096
#define BN_EPS_C 1e-5f

// ---------------- conv3x3 s2 p1 + bias + BN + ReLU -> xg[b][n][c] ----------------
__global__ __launch_bounds__(256) void k_conv(
    const float* __restrict__ x, const float* __restrict__ cw, const float* __restrict__ cb,
    const float* __restrict__ bng, const float* __restrict__ bnb, const float* __restrict__ bnm,
    const float* __restrict__ bnv, float* __restrict__ xg)
{
    int b = blockIdx.y, oh = blockIdx.x;
    int tid = threadIdx.x;
    int ow = tid & 63;
    int wg = __builtin_amdgcn_readfirstlane(tid >> 6);   // 0..3 -> oc group of 16
    float acc[16];
#pragma unroll
    for (int j = 0; j < 16; ++j) acc[j] = 0.f;
    const float* xb = x + (size_t)b * NC * NH * NW;
    int ih0 = 2 * oh - 1;
    for (int ic = 0; ic < 64; ++ic) {
        const float* xr = xb + (size_t)ic * (NH * NW);
        float v00, v01, v02, v10, v11, v12, v20, v21, v22;
        if (ih0 < 0) { v00 = v01 = v02 = 0.f; }
        else {
            const float* p = xr + ih0 * NW + 2 * ow;
            float2 t = *(const float2*)p;
            v01 = t.x; v02 = t.y;
            v00 = (ow == 0) ? 0.f : p[-1];
        }
        { const float* p = xr + (ih0 + 1) * NW + 2 * ow; float2 t = *(const float2*)p; v11 = t.x; v12 = t.y; v10 = (ow == 0) ? 0.f : p[-1]; }
        { const float* p = xr + (ih0 + 2) * NW + 2 * ow; float2 t = *(const float2*)p; v21 = t.x; v22 = t.y; v20 = (ow == 0) ? 0.f : p[-1]; }
        const float* wp = cw + ((size_t)(wg * 16) * 64 + ic) * 9;
#pragma unroll
        for (int j = 0; j < 16; ++j) {
            const float* wj = wp + (size_t)j * 576;
            acc[j] += wj[0] * v00 + wj[1] * v01 + wj[2] * v02
                    + wj[3] * v10 + wj[4] * v11 + wj[5] * v12
                    + wj[6] * v20 + wj[7] * v21 + wj[8] * v22;
        }
    }
    int n = oh * 64 + ow;
    float* outr = xg + ((size_t)b * NN + n) * 64;
#pragma unroll
    for (int j = 0; j < 16; ++j) {
        int oc = wg * 16 + j;
        float s = bng[oc] * rsqrtf(bnv[oc] + BN_EPS_C);
        float y = (acc[j] + cb[oc] - bnm[oc]) * s + bnb[oc];
        outr[oc] = fmaxf(y, 0.f);
    }
}

// ---------------- sobel |gx|,|gy| over (N, c) image per batch ----------------
__global__ __launch_bounds__(256) void k_sobel(
    const float* __restrict__ xg, float* __restrict__ sx, float* __restrict__ sy)
{
    __shared__ float t[66][66];   // rows n0-1..n0+64, cols shifted by +1, col 0/65 = pad
    int b = blockIdx.y;
    int n0 = blockIdx.x * 64;
    int tid = threadIdx.x;
    const float* xb = xg + (size_t)b * NN * 64;
    for (int idx = tid; idx < 66 * 64; idx += 256) {
        int r = idx >> 6, c = idx & 63;
        int n = n0 - 1 + r;
        float v = (n >= 0 && n < NN) ? xb[(size_t)n * 64 + c] : 0.f;
        t[r][c + 1] = v;
    }
    for (int idx = tid; idx < 66; idx += 256) { t[idx][0] = 0.f; t[idx][65] = 0.f; }
    __syncthreads();
    int c = tid & 63, rg = tid >> 6;
    int lc = c + 1;
    for (int i = 0; i < 16; ++i) {
        int r = rg * 16 + i;   // output row n0+r uses lds rows r, r+1, r+2
        float tm1 = t[r][lc - 1],     t0 = t[r][lc],     tp1 = t[r][lc + 1];
        float mm1 = t[r + 1][lc - 1],                    mp1 = t[r + 1][lc + 1];
        float bm1 = t[r + 2][lc - 1], b0 = t[r + 2][lc], bp1 = t[r + 2][lc + 1];
        float gx = (tp1 + 2.f * mp1 + bp1) - (tm1 + 2.f * mm1 + bm1);
        float gy = (bm1 + 2.f * b0 + bp1) - (tm1 + 2.f * t0 + tp1);
        size_t o = ((size_t)b * NN + n0 + r) * 64 + c;
        sx[o] = fabsf(gx);
        sy[o] = fabsf(gy);
    }
}

// ------------- logits (fp32) + batch-softmax + bf16 A + rowsum atomics -------------
// block: n-tile 64 (4 waves x 16 rows), m-tile 64 (lanes). all 4 batches per thread.
__global__ __launch_bounds__(256) void k_logits(
    const float* __restrict__ sx, const float* __restrict__ sy,
    __hip_bfloat16* __restrict__ A, float* __restrict__ rowsum)
{
    __shared__ float lds[4][64][65];   // sy staging; later reused as per-wave reduce buffer
    int tid = threadIdx.x;
    int lane = tid & 63;
    int w = __builtin_amdgcn_readfirstlane(tid >> 6);
    int m0 = blockIdx.x * 64, n0 = blockIdx.y * 64;
    for (int idx = tid; idx < 4 * 64 * 64; idx += 256) {
        int b = idx >> 12, rem = idx & 4095, r = rem >> 6, k = rem & 63;
        lds[b][r][k] = sy[((size_t)b * NN + m0 + r) * 64 + k];
    }
    __syncthreads();
    float acc[16][4];
#pragma unroll
    for (int i = 0; i < 16; ++i)
#pragma unroll
        for (int b = 0; b < 4; ++b) acc[i][b] = 0.f;
    int nw = n0 + w * 16;
    for (int k4 = 0; k4 < 16; ++k4) {
        float syv[4][4];
#pragma unroll
        for (int b = 0; b < 4; ++b)
#pragma unroll
            for (int k = 0; k < 4; ++k) syv[b][k] = lds[b][lane][k4 * 4 + k];
#pragma unroll
        for (int i = 0; i < 16; ++i) {
#pragma unroll
            for (int b = 0; b < 4; ++b) {
                // uniform address within wave -> should scalarize to s_load
                float4 sv = *(const float4*)(sx + ((size_t)b * NN + nw + i) * 64 + k4 * 4);
                acc[i][b] += sv.x * syv[b][0] + sv.y * syv[b][1] + sv.z * syv[b][2] + sv.w * syv[b][3];
            }
        }
    }
    __syncthreads();   // everyone done reading sy staging; reuse lds[w] as reduce buffer
    float* red = &lds[0][0][0] + (size_t)w * (64 * 65);
#pragma unroll
    for (int i = 0; i < 16; ++i) {
        float mx = fmaxf(fmaxf(acc[i][0], acc[i][1]), fmaxf(acc[i][2], acc[i][3]));
        float e0 = __expf(acc[i][0] - mx);
        float e1 = __expf(acc[i][1] - mx);
        float e2 = __expf(acc[i][2] - mx);
        float e3 = __expf(acc[i][3] - mx);
        float rz = 1.f / (e0 + e1 + e2 + e3);
        float a0 = e0 * rz, a1 = e1 * rz, a2 = e2 * rz, a3 = e3 * rz;
        int n = nw + i;
        size_t base = (size_t)n * NN + m0 + lane;
        A[(size_t)0 * NN * NN + base] = __float2bfloat16(a0);
        A[(size_t)1 * NN * NN + base] = __float2bfloat16(a1);
        A[(size_t)2 * NN * NN + base] = __float2bfloat16(a2);
        A[(size_t)3 * NN * NN + base] = __float2bfloat16(a3);
        red[(i * 4 + 0) * 65 + lane] = a0;
        red[(i * 4 + 1) * 65 + lane] = a1;
        red[(i * 4 + 2) * 65 + lane] = a2;
        red[(i * 4 + 3) * 65 + lane] = a3;
    }
    // row 'lane' of red = (i = lane>>2, b = lane&3); sum over 64 m-cols
    float s = 0.f;
    for (int mc = 0; mc < 64; ++mc) s += red[lane * 65 + mc];
    atomicAdd(&rowsum[(size_t)(lane & 3) * NN + nw + (lane >> 2)], s);
}

__global__ __launch_bounds__(256) void k_dinv(const float* __restrict__ rs, float* __restrict__ dinv)
{
    int i = blockIdx.x * 256 + threadIdx.x;
    dinv[i] = rsqrtf(rs[i] + 1.0f);
}

// ------- small GEMM: t'[m][o] = dinv[m] * sum_c h[m][c] fc[o][c]; write fp32 + bf16^T -------
__global__ __launch_bounds__(256) void k_small(
    const float* __restrict__ h, const float* __restrict__ fc, const float* __restrict__ dinv,
    __hip_bfloat16* __restrict__ tT, float* __restrict__ tf)
{
    int blk = blockIdx.x;            // 256 blocks
    int b = blk >> 6, m0 = (blk & 63) * 64;
    int tid = threadIdx.x;
    int mi = tid & 63, m = m0 + mi;
    int oq = __builtin_amdgcn_readfirstlane(tid >> 6);
    const float* hr = h + ((size_t)b * NN + m) * 64;
    float hv[64];
#pragma unroll
    for (int i = 0; i < 16; ++i) {
        float4 v = *(const float4*)(hr + 4 * i);
        hv[4 * i] = v.x; hv[4 * i + 1] = v.y; hv[4 * i + 2] = v.z; hv[4 * i + 3] = v.w;
    }
    float dv = dinv[(size_t)b * NN + m];
#pragma unroll
    for (int j = 0; j < 16; ++j) {
        int o = oq * 16 + j;
        const float* wr = fc + (size_t)o * 64;
        float a = 0.f;
#pragma unroll
        for (int c2 = 0; c2 < 64; ++c2) a += hv[c2] * wr[c2];
        a *= dv;
        tf[((size_t)b * NN + m) * 64 + o] = a;
        tT[((size_t)b * 64 + o) * NN + m] = __float2bfloat16(a);
    }
}

// ------- big GEMM: out[n][o] = act( dinv[n] * (sum_m A[n][m] t'[m][o] + t'[n][o]) ) -------
// block = one batch x 64 n-rows; 4 waves split K (each 1024); reduce in LDS.
__global__ __launch_bounds__(256) void k_big(
    const __hip_bfloat16* __restrict__ A, const __hip_bfloat16* __restrict__ tT,
    const float* __restrict__ tf, const float* __restrict__ dinv,
    float* __restrict__ outp, int relu)
{
    __shared__ float red[4][64][65];
    int blk = blockIdx.x;            // 256 blocks
    int b = blk >> 6, n0 = (blk & 63) * 64;
    int tid = threadIdx.x, lane = tid & 63;
    int w = __builtin_amdgcn_readfirstlane(tid >> 6);
    int l15 = lane & 15, lg = lane >> 4;
    f32x4 zero4 = {0.f, 0.f, 0.f, 0.f};
    f32x4 acc[4][4];
#pragma unroll
    for (int ti = 0; ti < 4; ++ti)
#pragma unroll
        for (int tj = 0; tj < 4; ++tj) acc[ti][tj] = zero4;
    const short* Ab = (const short*)A + (size_t)b * NN * NN;
    const short* Tb = (const short*)tT + (size_t)b * 64 * NN;
    size_t kbase = (size_t)w * 1024 + (size_t)lg * 8;

    bf16x8 a0[4], b0[4], a1[4], b1[4];
#define LOADF(aa, bb, kk_) do { \
    size_t kx = kbase + (size_t)(kk_) * 32; \
    _Pragma("unroll") \
    for (int t = 0; t < 4; ++t) (aa)[t] = *(const bf16x8*)(Ab + (size_t)(n0 + t * 16 + l15) * NN + kx); \
    _Pragma("unroll") \
    for (int t = 0; t < 4; ++t) (bb)[t] = *(const bf16x8*)(Tb + (size_t)(t * 16 + l15) * NN + kx); \
} while (0)
#define MFMA16(aa, bb) do { \
    _Pragma("unroll") \
    for (int ti = 0; ti < 4; ++ti) \
        _Pragma("unroll") \
        for (int tj = 0; tj < 4; ++tj) \
            acc[ti][tj] = __builtin_amdgcn_mfma_f32_16x16x32_bf16((aa)[ti], (bb)[tj], acc[ti][tj], 0, 0, 0); \
} while (0)

    LOADF(a0, b0, 0);
    for (int kk = 0; kk < 32; kk += 2) {
        LOADF(a1, b1, kk + 1);
        MFMA16(a0, b0);
        if (kk + 2 < 32) LOADF(a0, b0, kk + 2);
        MFMA16(a1, b1);
    }
#undef LOADF
#undef MFMA16
#pragma unroll
    for (int ti = 0; ti < 4; ++ti)
#pragma unroll
        for (int tj = 0; tj < 4; ++tj)
#pragma unroll
            for (int j = 0; j < 4; ++j)
                red[w][ti * 16 + lg * 4 + j][tj * 16 + l15] = acc[ti][tj][j];
    __syncthreads();
    int n = tid >> 2, o0 = (tid & 3) * 16;
    float dn = dinv[(size_t)b * NN + n0 + n];
    const float* tr = tf + ((size_t)b * NN + n0 + n) * 64;
    float* orow = outp + ((size_t)b * NN + n0 + n) * 64;
#pragma unroll
    for (int j = 0; j < 16; ++j) {
        int o = o0 + j;
        float u = red[0][n][o] + red[1][n][o] + red[2][n][o] + red[3][n][o];
        float vv = dn * (u + tr[o]);
        if (relu) vv = fmaxf(vv, 0.f);
        orow[o] = vv;
    }
}

// ------------- bilinear x2 upsample, align_corners; o3 is [b][n][ch] -------------
__global__ __launch_bounds__(256) void k_up(const float* __restrict__ o3, float* __restrict__ outp)
{
    int b = blockIdx.y, Y = blockIdx.x;
    int tid = threadIdx.x;
    int X = tid & 127, cg = tid >> 7;
    int iy = Y * 63; int y0 = iy / 127; float wy = (float)(iy - y0 * 127) * (1.f / 127.f);
    int y1 = min(y0 + 1, 63);
    int ix = X * 63; int x0 = ix / 127; float wx = (float)(ix - x0 * 127) * (1.f / 127.f);
    int x1 = min(x0 + 1, 63);
    const float* p00 = o3 + ((size_t)b * NN + y0 * 64 + x0) * 64;
    const float* p01 = o3 + ((size_t)b * NN + y0 * 64 + x1) * 64;
    const float* p10 = o3 + ((size_t)b * NN + y1 * 64 + x0) * 64;
    const float* p11 = o3 + ((size_t)b * NN + y1 * 64 + x1) * 64;
    float w00 = (1.f - wy) * (1.f - wx), w01 = (1.f - wy) * wx;
    float w10 = wy * (1.f - wx), w11 = wy * wx;
#pragma unroll
    for (int j = 0; j < 32; ++j) {
        int ch = cg * 32 + j;
        float v = w00 * p00[ch] + w01 * p01[ch] + w10 * p10[ch] + w11 * p11[ch];
        outp[(((size_t)b * 64 + ch) * 128 + Y) * 128 + X] = v;
    }
}

extern "C" void kernel_launch(void* const* d_in, const int* in_sizes, int n_in,
                              void* d_out, int out_size, void* d_ws, size_t ws_size,
                              hipStream_t stream)
{
    const float* x   = (const float*)d_in[0];
    const float* cw  = (const float*)d_in[1];
    const float* cb  = (const float*)d_in[2];
    const float* bng = (const float*)d_in[3];
    const float* bnb = (const float*)d_in[4];
    const float* bnm = (const float*)d_in[5];
    const float* bnv = (const float*)d_in[6];
    const float* fc1 = (const float*)d_in[7];
    const float* fc2 = (const float*)d_in[8];
    const float* fc3 = (const float*)d_in[9];
    float* outp = (float*)d_out;

    char* ws = (char*)d_ws;
    size_t off = 0;
    auto alloc = [&](size_t bytes) -> void* {
        void* p = ws + off;
        off += (bytes + 255) & ~(size_t)255;
        return p;
    };
    __hip_bfloat16* Abuf = (__hip_bfloat16*)alloc((size_t)NB * NN * NN * 2);
    float* xg     = (float*)alloc((size_t)NB * NN * 64 * 4);
    float* sxb    = (float*)alloc((size_t)NB * NN * 64 * 4);
    float* syb    = (float*)alloc((size_t)NB * NN * 64 * 4);
    __hip_bfloat16* tT = (__hip_bfloat16*)alloc((size_t)NB * 64 * NN * 2);
    float* tf     = (float*)alloc((size_t)NB * NN * 64 * 4);
    float* h1     = (float*)alloc((size_t)NB * NN * 64 * 4);
    float* h2     = (float*)alloc((size_t)NB * NN * 64 * 4);
    float* o3     = (float*)alloc((size_t)NB * NN * 64 * 4);
    float* rowsum = (float*)alloc((size_t)NB * NN * 4);
    float* dinvb  = (float*)alloc((size_t)NB * NN * 4);

    hipMemsetAsync(rowsum, 0, (size_t)NB * NN * 4, stream);

    k_conv<<<dim3(64, 4), 256, 0, stream>>>(x, cw, cb, bng, bnb, bnm, bnv, xg);
    k_sobel<<<dim3(64, 4), 256, 0, stream>>>(xg, sxb, syb);
    k_logits<<<dim3(64, 64), 256, 0, stream>>>(sxb, syb, Abuf, rowsum);
    k_dinv<<<64, 256, 0, stream>>>(rowsum, dinvb);

    k_small<<<256, 256, 0, stream>>>(xg, fc1, dinvb, tT, tf);
    k_big<<<256, 256, 0, stream>>>(Abuf, tT, tf, dinvb, h1, 1);
    k_small<<<256, 256, 0, stream>>>(h1, fc2, dinvb, tT, tf);
    k_big<<<256, 256, 0, stream>>>(Abuf, tT, tf, dinvb, h2, 1);
    k_small<<<256, 256, 0, stream>>>(h2, fc3, dinvb, tT, tf);
    k_big<<<256, 256, 0, stream>>>(Abuf, tT, tf, dinvb, o3, 0);

    k_up<<<dim3(128, 4), 256, 0, stream>>>(o3, outp);
}

// Round 2
// 566.996 us; speedup vs baseline: 1.8100x; 1.8100x over previous
//
#include <hip/hip_runtime.h>
#include <hip/hip_bf16.h>

typedef float f32x4 __attribute__((ext_vector_type(4)));
typedef short bf16x8 __attribute__((ext_vector_type(8)));

#define NB 4
#define NC 64
#define NH 128
#define NW 128
#define NN 4096
#define BN_EPS_C 1e-5f

// ---------------- conv3x3 s2 p1 + bias + BN + ReLU -> xg[b][n][c] ----------------
__global__ __launch_bounds__(256) void k_conv(
    const float* __restrict__ x, const float* __restrict__ cw, const float* __restrict__ cb,
    const float* __restrict__ bng, const float* __restrict__ bnb, const float* __restrict__ bnm,
    const float* __restrict__ bnv, float* __restrict__ xg)
{
    int b = blockIdx.y, oh = blockIdx.x;
    int tid = threadIdx.x;
    int ow = tid & 63;
    int wg = __builtin_amdgcn_readfirstlane(tid >> 6);   // 0..3 -> oc group of 16
    float acc[16];
#pragma unroll
    for (int j = 0; j < 16; ++j) acc[j] = 0.f;
    const float* xb = x + (size_t)b * NC * NH * NW;
    int ih0 = 2 * oh - 1;
    for (int ic = 0; ic < 64; ++ic) {
        const float* xr = xb + (size_t)ic * (NH * NW);
        float v00, v01, v02, v10, v11, v12, v20, v21, v22;
        if (ih0 < 0) { v00 = v01 = v02 = 0.f; }
        else {
            const float* p = xr + ih0 * NW + 2 * ow;
            float2 t = *(const float2*)p;
            v01 = t.x; v02 = t.y;
            v00 = (ow == 0) ? 0.f : p[-1];
        }
        { const float* p = xr + (ih0 + 1) * NW + 2 * ow; float2 t = *(const float2*)p; v11 = t.x; v12 = t.y; v10 = (ow == 0) ? 0.f : p[-1]; }
        { const float* p = xr + (ih0 + 2) * NW + 2 * ow; float2 t = *(const float2*)p; v21 = t.x; v22 = t.y; v20 = (ow == 0) ? 0.f : p[-1]; }
        const float* wp = cw + ((size_t)(wg * 16) * 64 + ic) * 9;
#pragma unroll
        for (int j = 0; j < 16; ++j) {
            const float* wj = wp + (size_t)j * 576;
            acc[j] += wj[0] * v00 + wj[1] * v01 + wj[2] * v02
                    + wj[3] * v10 + wj[4] * v11 + wj[5] * v12
                    + wj[6] * v20 + wj[7] * v21 + wj[8] * v22;
        }
    }
    int n = oh * 64 + ow;
    float* outr = xg + ((size_t)b * NN + n) * 64;
#pragma unroll
    for (int j = 0; j < 16; ++j) {
        int oc = wg * 16 + j;
        float s = bng[oc] * rsqrtf(bnv[oc] + BN_EPS_C);
        float y = (acc[j] + cb[oc] - bnm[oc]) * s + bnb[oc];
        outr[oc] = fmaxf(y, 0.f);
    }
}

// ------- sobel |gx|,|gy| over (N, c) image per batch -> split bf16 hi/lo -------
__global__ __launch_bounds__(256) void k_sobel(
    const float* __restrict__ xg,
    __hip_bfloat16* __restrict__ xh, __hip_bfloat16* __restrict__ xl,
    __hip_bfloat16* __restrict__ yh, __hip_bfloat16* __restrict__ yl)
{
    __shared__ float t[66][66];   // rows n0-1..n0+64, cols shifted by +1, col 0/65 = pad
    int b = blockIdx.y;
    int n0 = blockIdx.x * 64;
    int tid = threadIdx.x;
    const float* xb = xg + (size_t)b * NN * 64;
    for (int idx = tid; idx < 66 * 64; idx += 256) {
        int r = idx >> 6, c = idx & 63;
        int n = n0 - 1 + r;
        float v = (n >= 0 && n < NN) ? xb[(size_t)n * 64 + c] : 0.f;
        t[r][c + 1] = v;
    }
    for (int idx = tid; idx < 66; idx += 256) { t[idx][0] = 0.f; t[idx][65] = 0.f; }
    __syncthreads();
    int c = tid & 63, rg = tid >> 6;
    int lc = c + 1;
    for (int i = 0; i < 16; ++i) {
        int r = rg * 16 + i;   // output row n0+r uses lds rows r, r+1, r+2
        float tm1 = t[r][lc - 1],     t0 = t[r][lc],     tp1 = t[r][lc + 1];
        float mm1 = t[r + 1][lc - 1],                    mp1 = t[r + 1][lc + 1];
        float bm1 = t[r + 2][lc - 1], b0 = t[r + 2][lc], bp1 = t[r + 2][lc + 1];
        float gx = (tp1 + 2.f * mp1 + bp1) - (tm1 + 2.f * mm1 + bm1);
        float gy = (bm1 + 2.f * b0 + bp1) - (tm1 + 2.f * t0 + tp1);
        float ax = fabsf(gx), ay = fabsf(gy);
        size_t o = ((size_t)b * NN + n0 + r) * 64 + c;
        __hip_bfloat16 h1 = __float2bfloat16(ax);
        xh[o] = h1;
        xl[o] = __float2bfloat16(ax - __bfloat162float(h1));
        __hip_bfloat16 h2 = __float2bfloat16(ay);
        yh[o] = h2;
        yl[o] = __float2bfloat16(ay - __bfloat162float(h2));
    }
}

// ------- logits via MFMA split-bf16 (hh+hl+lh) + batch-softmax + bf16 A + rowsums -------
// block = 64(n) x 64(m) tile, all 4 batches; 4 waves = 4 n-strips of 16.
__global__ __launch_bounds__(256) void k_logits(
    const __hip_bfloat16* __restrict__ xh_, const __hip_bfloat16* __restrict__ xl_,
    const __hip_bfloat16* __restrict__ yh_, const __hip_bfloat16* __restrict__ yl_,
    __hip_bfloat16* __restrict__ A, float* __restrict__ rowsum)
{
    __shared__ ushort st[4][64][68];
    const ushort* xh = (const ushort*)xh_;
    const ushort* xl = (const ushort*)xl_;
    const ushort* yh = (const ushort*)yh_;
    const ushort* yl = (const ushort*)yl_;
    int tid = threadIdx.x;
    int lane = tid & 63;
    int w = __builtin_amdgcn_readfirstlane(tid >> 6);
    int m0 = blockIdx.x * 64, n0 = blockIdx.y * 64;
    int l15 = lane & 15, lg = lane >> 4;
    int nrow = n0 + w * 16 + l15;
    int koff = lg * 8;

    f32x4 acc[4][4];   // [b][mt]
#pragma unroll
    for (int b = 0; b < 4; ++b)
#pragma unroll
        for (int mt = 0; mt < 4; ++mt) acc[b][mt] = (f32x4){0.f, 0.f, 0.f, 0.f};

#pragma unroll
    for (int b = 0; b < 4; ++b) {
        const ushort* pah = xh + ((size_t)b * NN + nrow) * 64 + koff;
        const ushort* pal = xl + ((size_t)b * NN + nrow) * 64 + koff;
        bf16x8 ah0 = *(const bf16x8*)pah;
        bf16x8 ah1 = *(const bf16x8*)(pah + 32);
        bf16x8 al0 = *(const bf16x8*)pal;
        bf16x8 al1 = *(const bf16x8*)(pal + 32);
#pragma unroll
        for (int mt = 0; mt < 4; ++mt) {
            int mrow = m0 + mt * 16 + l15;
            const ushort* pbh = yh + ((size_t)b * NN + mrow) * 64 + koff;
            const ushort* pbl = yl + ((size_t)b * NN + mrow) * 64 + koff;
            bf16x8 bh0 = *(const bf16x8*)pbh;
            bf16x8 bh1 = *(const bf16x8*)(pbh + 32);
            bf16x8 bl0 = *(const bf16x8*)pbl;
            bf16x8 bl1 = *(const bf16x8*)(pbl + 32);
            f32x4 a = acc[b][mt];
            a = __builtin_amdgcn_mfma_f32_16x16x32_bf16(ah0, bh0, a, 0, 0, 0);
            a = __builtin_amdgcn_mfma_f32_16x16x32_bf16(ah1, bh1, a, 0, 0, 0);
            a = __builtin_amdgcn_mfma_f32_16x16x32_bf16(ah0, bl0, a, 0, 0, 0);
            a = __builtin_amdgcn_mfma_f32_16x16x32_bf16(ah1, bl1, a, 0, 0, 0);
            a = __builtin_amdgcn_mfma_f32_16x16x32_bf16(al0, bh0, a, 0, 0, 0);
            a = __builtin_amdgcn_mfma_f32_16x16x32_bf16(al1, bh1, a, 0, 0, 0);
            acc[b][mt] = a;
        }
    }

    // batch-softmax in-register; stage bf16 A tile in LDS; accumulate row partials
    float rsum[4][4];
#pragma unroll
    for (int b = 0; b < 4; ++b)
#pragma unroll
        for (int j = 0; j < 4; ++j) rsum[b][j] = 0.f;

#pragma unroll
    for (int mt = 0; mt < 4; ++mt) {
#pragma unroll
        for (int j = 0; j < 4; ++j) {
            float v0 = acc[0][mt][j], v1 = acc[1][mt][j], v2 = acc[2][mt][j], v3 = acc[3][mt][j];
            float mx = fmaxf(fmaxf(v0, v1), fmaxf(v2, v3));
            float e0 = __expf(v0 - mx);
            float e1 = __expf(v1 - mx);
            float e2 = __expf(v2 - mx);
            float e3 = __expf(v3 - mx);
            float rz = 1.f / (e0 + e1 + e2 + e3);
            float a0 = e0 * rz, a1 = e1 * rz, a2 = e2 * rz, a3 = e3 * rz;
            rsum[0][j] += a0; rsum[1][j] += a1; rsum[2][j] += a2; rsum[3][j] += a3;
            int row = w * 16 + lg * 4 + j;
            int col = mt * 16 + l15;
            __hip_bfloat16 q0 = __float2bfloat16(a0);
            __hip_bfloat16 q1 = __float2bfloat16(a1);
            __hip_bfloat16 q2 = __float2bfloat16(a2);
            __hip_bfloat16 q3 = __float2bfloat16(a3);
            st[0][row][col] = *(ushort*)&q0;
            st[1][row][col] = *(ushort*)&q1;
            st[2][row][col] = *(ushort*)&q2;
            st[3][row][col] = *(ushort*)&q3;
        }
    }

    // rowsum: reduce 16 lanes (cols) per row, one atomic per (b,row)
#pragma unroll
    for (int b = 0; b < 4; ++b) {
#pragma unroll
        for (int j = 0; j < 4; ++j) {
            float s = rsum[b][j];
            s += __shfl_xor(s, 1);
            s += __shfl_xor(s, 2);
            s += __shfl_xor(s, 4);
            s += __shfl_xor(s, 8);
            if (l15 == b * 4 + j)
                atomicAdd(&rowsum[(size_t)b * NN + n0 + w * 16 + lg * 4 + j], s);
        }
    }

    __syncthreads();
    // write A: 2048 chunks of 16B; consecutive lanes -> consecutive chunks (128B runs)
#pragma unroll
    for (int i = 0; i < 8; ++i) {
        int c = tid + i * 256;
        int b = c >> 9;
        int rr = (c >> 3) & 63;
        int c8 = c & 7;
        bf16x8 v = *(const bf16x8*)&st[b][rr][c8 * 8];
        *(bf16x8*)((ushort*)A + (size_t)b * NN * NN + (size_t)(n0 + rr) * NN + m0 + c8 * 8) = v;
    }
}

__global__ __launch_bounds__(256) void k_dinv(const float* __restrict__ rs, float* __restrict__ dinv)
{
    int i = blockIdx.x * 256 + threadIdx.x;
    dinv[i] = rsqrtf(rs[i] + 1.0f);
}

// ------- small GEMM: t'[m][o] = dinv[m] * sum_c h[m][c] fc[o][c]; write fp32 + bf16^T -------
__global__ __launch_bounds__(256) void k_small(
    const float* __restrict__ h, const float* __restrict__ fc, const float* __restrict__ dinv,
    __hip_bfloat16* __restrict__ tT, float* __restrict__ tf)
{
    int blk = blockIdx.x;            // 256 blocks
    int b = blk >> 6, m0 = (blk & 63) * 64;
    int tid = threadIdx.x;
    int mi = tid & 63, m = m0 + mi;
    int oq = __builtin_amdgcn_readfirstlane(tid >> 6);
    const float* hr = h + ((size_t)b * NN + m) * 64;
    float hv[64];
#pragma unroll
    for (int i = 0; i < 16; ++i) {
        float4 v = *(const float4*)(hr + 4 * i);
        hv[4 * i] = v.x; hv[4 * i + 1] = v.y; hv[4 * i + 2] = v.z; hv[4 * i + 3] = v.w;
    }
    float dv = dinv[(size_t)b * NN + m];
#pragma unroll
    for (int j = 0; j < 16; ++j) {
        int o = oq * 16 + j;
        const float* wr = fc + (size_t)o * 64;
        float a = 0.f;
#pragma unroll
        for (int c2 = 0; c2 < 64; ++c2) a += hv[c2] * wr[c2];
        a *= dv;
        tf[((size_t)b * NN + m) * 64 + o] = a;
        tT[((size_t)b * 64 + o) * NN + m] = __float2bfloat16(a);
    }
}

// ------- big GEMM: out[n][o] = act( dinv[n] * (sum_m A[n][m] t'[m][o] + t'[n][o]) ) -------
__global__ __launch_bounds__(256) void k_big(
    const __hip_bfloat16* __restrict__ A, const __hip_bfloat16* __restrict__ tT,
    const float* __restrict__ tf, const float* __restrict__ dinv,
    float* __restrict__ outp, int relu)
{
    __shared__ float red[4][64][65];
    int blk = blockIdx.x;            // 256 blocks
    int b = blk >> 6, n0 = (blk & 63) * 64;
    int tid = threadIdx.x, lane = tid & 63;
    int w = __builtin_amdgcn_readfirstlane(tid >> 6);
    int l15 = lane & 15, lg = lane >> 4;
    f32x4 zero4 = {0.f, 0.f, 0.f, 0.f};
    f32x4 acc[4][4];
#pragma unroll
    for (int ti = 0; ti < 4; ++ti)
#pragma unroll
        for (int tj = 0; tj < 4; ++tj) acc[ti][tj] = zero4;
    const short* Ab = (const short*)A + (size_t)b * NN * NN;
    const short* Tb = (const short*)tT + (size_t)b * 64 * NN;
    size_t kbase = (size_t)w * 1024 + (size_t)lg * 8;

    bf16x8 a0[4], b0[4], a1[4], b1[4];
#define LOADF(aa, bb, kk_) do { \
    size_t kx = kbase + (size_t)(kk_) * 32; \
    _Pragma("unroll") \
    for (int t = 0; t < 4; ++t) (aa)[t] = *(const bf16x8*)(Ab + (size_t)(n0 + t * 16 + l15) * NN + kx); \
    _Pragma("unroll") \
    for (int t = 0; t < 4; ++t) (bb)[t] = *(const bf16x8*)(Tb + (size_t)(t * 16 + l15) * NN + kx); \
} while (0)
#define MFMA16(aa, bb) do { \
    _Pragma("unroll") \
    for (int ti = 0; ti < 4; ++ti) \
        _Pragma("unroll") \
        for (int tj = 0; tj < 4; ++tj) \
            acc[ti][tj] = __builtin_amdgcn_mfma_f32_16x16x32_bf16((aa)[ti], (bb)[tj], acc[ti][tj], 0, 0, 0); \
} while (0)

    LOADF(a0, b0, 0);
    for (int kk = 0; kk < 32; kk += 2) {
        LOADF(a1, b1, kk + 1);
        MFMA16(a0, b0);
        if (kk + 2 < 32) LOADF(a0, b0, kk + 2);
        MFMA16(a1, b1);
    }
#undef LOADF
#undef MFMA16
#pragma unroll
    for (int ti = 0; ti < 4; ++ti)
#pragma unroll
        for (int tj = 0; tj < 4; ++tj)
#pragma unroll
            for (int j = 0; j < 4; ++j)
                red[w][ti * 16 + lg * 4 + j][tj * 16 + l15] = acc[ti][tj][j];
    __syncthreads();
    int n = tid >> 2, o0 = (tid & 3) * 16;
    float dn = dinv[(size_t)b * NN + n0 + n];
    const float* tr = tf + ((size_t)b * NN + n0 + n) * 64;
    float* orow = outp + ((size_t)b * NN + n0 + n) * 64;
#pragma unroll
    for (int j = 0; j < 16; ++j) {
        int o = o0 + j;
        float u = red[0][n][o] + red[1][n][o] + red[2][n][o] + red[3][n][o];
        float vv = dn * (u + tr[o]);
        if (relu) vv = fmaxf(vv, 0.f);
        orow[o] = vv;
    }
}

// ------------- bilinear x2 upsample, align_corners; o3 is [b][n][ch] -------------
__global__ __launch_bounds__(256) void k_up(const float* __restrict__ o3, float* __restrict__ outp)
{
    int b = blockIdx.y, Y = blockIdx.x;
    int tid = threadIdx.x;
    int X = tid & 127, cg = tid >> 7;
    int iy = Y * 63; int y0 = iy / 127; float wy = (float)(iy - y0 * 127) * (1.f / 127.f);
    int y1 = min(y0 + 1, 63);
    int ix = X * 63; int x0 = ix / 127; float wx = (float)(ix - x0 * 127) * (1.f / 127.f);
    int x1 = min(x0 + 1, 63);
    const float* p00 = o3 + ((size_t)b * NN + y0 * 64 + x0) * 64;
    const float* p01 = o3 + ((size_t)b * NN + y0 * 64 + x1) * 64;
    const float* p10 = o3 + ((size_t)b * NN + y1 * 64 + x0) * 64;
    const float* p11 = o3 + ((size_t)b * NN + y1 * 64 + x1) * 64;
    float w00 = (1.f - wy) * (1.f - wx), w01 = (1.f - wy) * wx;
    float w10 = wy * (1.f - wx), w11 = wy * wx;
#pragma unroll
    for (int j = 0; j < 32; ++j) {
        int ch = cg * 32 + j;
        float v = w00 * p00[ch] + w01 * p01[ch] + w10 * p10[ch] + w11 * p11[ch];
        outp[(((size_t)b * 64 + ch) * 128 + Y) * 128 + X] = v;
    }
}

extern "C" void kernel_launch(void* const* d_in, const int* in_sizes, int n_in,
                              void* d_out, int out_size, void* d_ws, size_t ws_size,
                              hipStream_t stream)
{
    const float* x   = (const float*)d_in[0];
    const float* cw  = (const float*)d_in[1];
    const float* cb  = (const float*)d_in[2];
    const float* bng = (const float*)d_in[3];
    const float* bnb = (const float*)d_in[4];
    const float* bnm = (const float*)d_in[5];
    const float* bnv = (const float*)d_in[6];
    const float* fc1 = (const float*)d_in[7];
    const float* fc2 = (const float*)d_in[8];
    const float* fc3 = (const float*)d_in[9];
    float* outp = (float*)d_out;

    char* ws = (char*)d_ws;
    size_t off = 0;
    auto alloc = [&](size_t bytes) -> void* {
        void* p = ws + off;
        off += (bytes + 255) & ~(size_t)255;
        return p;
    };
    __hip_bfloat16* Abuf = (__hip_bfloat16*)alloc((size_t)NB * NN * NN * 2);
    float* xg     = (float*)alloc((size_t)NB * NN * 64 * 4);
    __hip_bfloat16* sxh = (__hip_bfloat16*)alloc((size_t)NB * NN * 64 * 2);
    __hip_bfloat16* sxl = (__hip_bfloat16*)alloc((size_t)NB * NN * 64 * 2);
    __hip_bfloat16* syh = (__hip_bfloat16*)alloc((size_t)NB * NN * 64 * 2);
    __hip_bfloat16* syl = (__hip_bfloat16*)alloc((size_t)NB * NN * 64 * 2);
    __hip_bfloat16* tT = (__hip_bfloat16*)alloc((size_t)NB * 64 * NN * 2);
    float* tf     = (float*)alloc((size_t)NB * NN * 64 * 4);
    float* h1     = (float*)alloc((size_t)NB * NN * 64 * 4);
    float* h2     = (float*)alloc((size_t)NB * NN * 64 * 4);
    float* o3     = (float*)alloc((size_t)NB * NN * 64 * 4);
    float* rowsum = (float*)alloc((size_t)NB * NN * 4);
    float* dinvb  = (float*)alloc((size_t)NB * NN * 4);

    hipMemsetAsync(rowsum, 0, (size_t)NB * NN * 4, stream);

    k_conv<<<dim3(64, 4), 256, 0, stream>>>(x, cw, cb, bng, bnb, bnm, bnv, xg);
    k_sobel<<<dim3(64, 4), 256, 0, stream>>>(xg, sxh, sxl, syh, syl);
    k_logits<<<dim3(64, 64), 256, 0, stream>>>(sxh, sxl, syh, syl, Abuf, rowsum);
    k_dinv<<<64, 256, 0, stream>>>(rowsum, dinvb);

    k_small<<<256, 256, 0, stream>>>(xg, fc1, dinvb, tT, tf);
    k_big<<<256, 256, 0, stream>>>(Abuf, tT, tf, dinvb, h1, 1);
    k_small<<<256, 256, 0, stream>>>(h1, fc2, dinvb, tT, tf);
    k_big<<<256, 256, 0, stream>>>(Abuf, tT, tf, dinvb, h2, 1);
    k_small<<<256, 256, 0, stream>>>(h2, fc3, dinvb, tT, tf);
    k_big<<<256, 256, 0, stream>>>(Abuf, tT, tf, dinvb, o3, 0);

    k_up<<<dim3(128, 4), 256, 0, stream>>>(o3, outp);
}